// Round 13
// baseline (503.522 us; speedup 1.0000x reference)
//
#include <hip/hip_runtime.h>
#include <hip/hip_fp16.h>

typedef _Float16 half8v __attribute__((ext_vector_type(8)));
typedef _Float16 half4v __attribute__((ext_vector_type(4)));
typedef _Float16 half2v __attribute__((ext_vector_type(2)));
typedef float f32x4 __attribute__((ext_vector_type(4)));

#define NBIN 1024

// ---------------- fused: transpose-convert W1/W2/W3 to fp16 Wt[N][128] + zero cnt/hist ----------------

__global__ void cvt_wz(const float* __restrict__ W1, const float* __restrict__ W2,
                       const float* __restrict__ W3,
                       _Float16* __restrict__ Wt1, _Float16* __restrict__ Wt2,
                       _Float16* __restrict__ Wt3,
                       int* __restrict__ cnt, int* __restrict__ hist, int n) {
    int i = blockIdx.x * blockDim.x + threadIdx.x;
    if (i < 16384) {
        int nn = i >> 7, kk = i & 127;
        Wt1[i] = (_Float16)W1[kk * 128 + nn];
    } else if (i < 32768) {
        int j = i - 16384; int nn = j >> 7, kk = j & 127;
        Wt2[j] = (_Float16)W2[kk * 128 + nn];
    } else if (i < 40960) {
        int j = i - 32768; int nn = j >> 7, kk = j & 127;
        Wt3[j] = (_Float16)W3[kk * 64 + nn];
    }
    if (i < NBIN) hist[i] = 0;
    int z = i - 40960;
    if (z >= 0 && z < n) cnt[z] = 0;
}

// ---------------- degree count; atomic's return value IS the edge's rank in its row ----------------

__global__ void count_rank(const int* __restrict__ dst, int E, int* __restrict__ cnt,
                           unsigned short* __restrict__ rank) {
    int e = blockIdx.x * blockDim.x + threadIdx.x;
    if (e < E) rank[e] = (unsigned short)atomicAdd(&cnt[dst[e]], 1);
}

// scanA: block-local exclusive scan of cnt + dis = rsqrt(deg+1) + degree histogram
__global__ __launch_bounds__(256) void scanA(const int* __restrict__ cnt,
                                             int* __restrict__ row_ptr,
                                             int* __restrict__ blockSums,
                                             float* __restrict__ dis,
                                             int* __restrict__ hist, int n) {
    __shared__ int s[256];
    int t = threadIdx.x;
    int base = blockIdx.x * 1024 + t * 4;
    int v0 = (base + 0 < n) ? cnt[base + 0] : 0;
    int v1 = (base + 1 < n) ? cnt[base + 1] : 0;
    int v2 = (base + 2 < n) ? cnt[base + 2] : 0;
    int v3 = (base + 3 < n) ? cnt[base + 3] : 0;
    if (base + 0 < n) { dis[base + 0] = rsqrtf((float)(v0 + 1)); atomicAdd(&hist[min(v0, NBIN - 1)], 1); }
    if (base + 1 < n) { dis[base + 1] = rsqrtf((float)(v1 + 1)); atomicAdd(&hist[min(v1, NBIN - 1)], 1); }
    if (base + 2 < n) { dis[base + 2] = rsqrtf((float)(v2 + 1)); atomicAdd(&hist[min(v2, NBIN - 1)], 1); }
    if (base + 3 < n) { dis[base + 3] = rsqrtf((float)(v3 + 1)); atomicAdd(&hist[min(v3, NBIN - 1)], 1); }
    int tsum = v0 + v1 + v2 + v3;
    s[t] = tsum;
    __syncthreads();
    for (int off = 1; off < 256; off <<= 1) {
        int u = (t >= off) ? s[t - off] : 0;
        __syncthreads();
        s[t] += u;
        __syncthreads();
    }
    int excl = s[t] - tsum;
    if (base + 0 < n) row_ptr[base + 0] = excl;
    if (base + 1 < n) row_ptr[base + 1] = excl + v0;
    if (base + 2 < n) row_ptr[base + 2] = excl + v0 + v1;
    if (base + 3 < n) row_ptr[base + 3] = excl + v0 + v1 + v2;
    if (t == 255) blockSums[blockIdx.x] = s[255];
}

// scanC with inlined block-sum scan (B <= 64 blocks)
__global__ __launch_bounds__(256) void scanC(int* __restrict__ row_ptr,
                                             const int* __restrict__ blockSums,
                                             int n, int E, int B) {
    __shared__ int soff;
    int t = threadIdx.x;
    if (t < 64) {
        int v = (t < B) ? blockSums[t] : 0;
        int orig = v;
        for (int off = 1; off < 64; off <<= 1) {
            int u = __shfl_up(v, off, 64);
            if (t >= off) v += u;
        }
        if (t == (int)blockIdx.x) soff = v - orig;
    }
    __syncthreads();
    int off = soff;
    int base = blockIdx.x * 1024 + t * 4;
    #pragma unroll
    for (int j = 0; j < 4; ++j)
        if (base + j < n) row_ptr[base + j] += off;
    if (blockIdx.x == 0 && t == 0) row_ptr[n] = E;
}

// in-place exclusive scan of the 1024-bin degree histogram (single block)
__global__ __launch_bounds__(256) void scan_hist(int* __restrict__ hist) {
    __shared__ int s[256];
    int t = threadIdx.x;
    int v0 = hist[t * 4], v1 = hist[t * 4 + 1], v2 = hist[t * 4 + 2], v3 = hist[t * 4 + 3];
    int tsum = v0 + v1 + v2 + v3;
    s[t] = tsum;
    __syncthreads();
    for (int off = 1; off < 256; off <<= 1) {
        int u = (t >= off) ? s[t - off] : 0;
        __syncthreads();
        s[t] += u;
        __syncthreads();
    }
    int excl = s[t] - tsum;
    hist[t * 4 + 0] = excl;
    hist[t * 4 + 1] = excl + v0;
    hist[t * 4 + 2] = excl + v0 + v1;
    hist[t * 4 + 3] = excl + v0 + v1 + v2;
}

// order[] = node ids bucketed by degree (equal-degree nodes land in the same blocks)
__global__ void scatter_order(const int* __restrict__ cnt, int* __restrict__ histoff,
                              int* __restrict__ order, int n) {
    int i = blockIdx.x * blockDim.x + threadIdx.x;
    if (i >= n) return;
    int bin = min(cnt[i], NBIN - 1);
    int pos = atomicAdd(&histoff[bin], 1);
    order[pos] = i;
}

// atomic-free CSR fill: slot = row_ptr[d] + rank[e]
__global__ void fill_nr(const int* __restrict__ src, const int* __restrict__ dst,
                        const unsigned short* __restrict__ rank, int E,
                        const int* __restrict__ row_ptr, const float* __restrict__ dis,
                        unsigned int* __restrict__ edges) {
    int e = blockIdx.x * blockDim.x + threadIdx.x;
    if (e >= E) return;
    int d = dst[e], s = src[e];
    int slot = row_ptr[d] + (int)rank[e];
    float coef = dis[s] * dis[d];
    edges[slot] = (unsigned)s |
                  ((unsigned)__half_as_ushort(__float2half_rn(coef)) << 16);
}

__device__ __forceinline__ void unpack_edge(unsigned int w, int& s, float& c) {
    s = (int)(w & 0xffffu);
    c = __half2float(__ushort_as_half((unsigned short)(w >> 16)));
}

// ---------------- MFMA GEMM layer 1: Y[M,128](fp16) = f32 x @ Wt1[128][128] ----------------

template <int N, bool F32IN>
__global__ __launch_bounds__(256) void gemm_mfma(const void* __restrict__ Xin,
                                                 const _Float16* __restrict__ Wt,
                                                 _Float16* __restrict__ Y, int M) {
    constexpr int NT = N / 16;
    int wave = threadIdx.x >> 6;
    int lane = threadIdx.x & 63;
    int m0 = blockIdx.x * 64 + wave * 16;
    int r = lane & 15;
    int kb = lane >> 4;
    int ar = m0 + r; if (ar >= M) ar = M - 1;
    f32x4 acc[NT] = {};
    #pragma unroll
    for (int kk = 0; kk < 128; kk += 32) {
        half8v a;
        if constexpr (F32IN) {
            const float* arow = (const float*)Xin + (size_t)ar * 128 + kb * 8 + kk;
            float4 f0 = *(const float4*)arow;
            float4 f1 = *(const float4*)(arow + 4);
            a = (half8v){(_Float16)f0.x, (_Float16)f0.y, (_Float16)f0.z, (_Float16)f0.w,
                         (_Float16)f1.x, (_Float16)f1.y, (_Float16)f1.z, (_Float16)f1.w};
        } else {
            a = *(const half8v*)((const _Float16*)Xin + (size_t)ar * 128 + kb * 8 + kk);
        }
        #pragma unroll
        for (int c = 0; c < NT; ++c) {
            half8v b = *(const half8v*)(Wt + (size_t)(c * 16 + r) * 128 + kk + kb * 8);
            acc[c] = __builtin_amdgcn_mfma_f32_16x16x32_f16(a, b, acc[c], 0, 0, 0);
        }
    }
    #pragma unroll
    for (int j = 0; j < 4; ++j) {
        int row = m0 + kb * 4 + j;
        if (row < M) {
            #pragma unroll
            for (int c = 0; c < NT; ++c)
                Y[(size_t)row * N + c * 16 + r] = (_Float16)acc[c][j];
        }
    }
}

// ---------------- FUSED agg(D=128) + GEMM over degree-sorted nodes ----------------
// 1024 threads = 16 waves; one node per wave, node = order[blockIdx*16 + wave] so all
// 16 nodes in a block have ~equal degree (barrier waits ~nothing). As[16][136] fp16;
// wave w < NOUT/16 then computes col-tile w of the 16x128 @ 128xNOUT product.

template <int NOUT>
__global__ __launch_bounds__(1024) void agg_gemm(const __half2* __restrict__ hp,
                                                 const int* __restrict__ row_ptr,
                                                 const unsigned int* __restrict__ edges,
                                                 const float* __restrict__ dis,
                                                 const float* __restrict__ bias,
                                                 const _Float16* __restrict__ Wt,
                                                 const int* __restrict__ order,
                                                 _Float16* __restrict__ Y, int n) {
    __shared__ _Float16 As[16][136];
    __shared__ int nid[16];
    int t = threadIdx.x;
    int wave = t >> 6;
    int lane = t & 63;
    int m0 = blockIdx.x * 16;
    int node = (m0 + wave < n) ? order[m0 + wave] : -1;
    if (lane == 0) nid[wave] = node;
    float ox = 0.f, oy = 0.f;
    if (node >= 0) {
        int beg = row_ptr[node], end = row_ptr[node + 1];
        float di = dis[node];
        float cs = di * di;
        float2 sv = __half22float2(hp[(size_t)node * 64 + lane]);
        float2 a0 = {cs * sv.x, cs * sv.y};
        float2 a1 = {0.f, 0.f}, a2 = {0.f, 0.f}, a3 = {0.f, 0.f};
        int e = beg;
        for (; e + 4 <= end; e += 4) {
            unsigned int w0 = edges[e], w1 = edges[e + 1], w2 = edges[e + 2], w3 = edges[e + 3];
            int s0, s1, s2, s3; float c0, c1, c2, c3;
            unpack_edge(w0, s0, c0); unpack_edge(w1, s1, c1);
            unpack_edge(w2, s2, c2); unpack_edge(w3, s3, c3);
            float2 u0 = __half22float2(hp[(size_t)s0 * 64 + lane]);
            float2 u1 = __half22float2(hp[(size_t)s1 * 64 + lane]);
            float2 u2 = __half22float2(hp[(size_t)s2 * 64 + lane]);
            float2 u3 = __half22float2(hp[(size_t)s3 * 64 + lane]);
            a0.x += c0 * u0.x; a0.y += c0 * u0.y;
            a1.x += c1 * u1.x; a1.y += c1 * u1.y;
            a2.x += c2 * u2.x; a2.y += c2 * u2.y;
            a3.x += c3 * u3.x; a3.y += c3 * u3.y;
        }
        for (; e < end; ++e) {
            int s0; float c0;
            unpack_edge(edges[e], s0, c0);
            float2 u0 = __half22float2(hp[(size_t)s0 * 64 + lane]);
            a0.x += c0 * u0.x; a0.y += c0 * u0.y;
        }
        float2 bv = ((const float2*)bias)[lane];
        ox = fmaxf(a0.x + a1.x + a2.x + a3.x + bv.x, 0.f);
        oy = fmaxf(a0.y + a1.y + a2.y + a3.y + bv.y, 0.f);
    }
    *(half2v*)&As[wave][2 * lane] = (half2v){(_Float16)ox, (_Float16)oy};
    __syncthreads();
    constexpr int CT = NOUT / 16;  // 8 or 4 col tiles
    if (wave < CT) {
        int r = lane & 15;
        int kb = lane >> 4;
        f32x4 acc = {};
        #pragma unroll
        for (int kk = 0; kk < 128; kk += 32) {
            half8v a = *(const half8v*)&As[r][kb * 8 + kk];
            half8v b = *(const half8v*)(Wt + (size_t)(wave * 16 + r) * 128 + kk + kb * 8);
            acc = __builtin_amdgcn_mfma_f32_16x16x32_f16(a, b, acc, 0, 0, 0);
        }
        #pragma unroll
        for (int j = 0; j < 4; ++j) {
            int row = nid[kb * 4 + j];
            if (row >= 0)
                Y[(size_t)row * NOUT + wave * 16 + r] = (_Float16)acc[j];
        }
    }
}

// ---------------- FUSED agg(D=64) + projection + relu + row-normalize (degree-sorted) ----------------

__global__ __launch_bounds__(256) void agg_proj(const _Float16* __restrict__ h,
                                                const int* __restrict__ row_ptr,
                                                const unsigned int* __restrict__ edges,
                                                const float* __restrict__ dis,
                                                const float* __restrict__ b3,
                                                const float* __restrict__ Wp,
                                                const int* __restrict__ order,
                                                float* __restrict__ P, int n) {
    __shared__ float oT[64 * 68];
    __shared__ float Ws[64 * 64];
    int t = threadIdx.x;
    int base = blockIdx.x * 64;
    for (int j = t * 4; j < 4096; j += 1024)
        *(float4*)&Ws[j] = *(const float4*)&Wp[j];
    int cg = t & 15;   // col group: dims 4*cg..+3
    int ng = t >> 4;   // node-in-pass 0..15
    int c0 = cg * 4;
    float4 bv = *(const float4*)&b3[c0];
    #pragma unroll
    for (int pass = 0; pass < 4; ++pass) {
        int ni = pass * 16 + ng;
        int node = (base + ni < n) ? order[base + ni] : -1;
        float ax = 0.f, ay = 0.f, az = 0.f, aw = 0.f;
        if (node >= 0) {
            int beg = row_ptr[node], end = row_ptr[node + 1];
            float di = dis[node];
            float cs = di * di;
            half4v sv = *(const half4v*)&h[(size_t)node * 64 + c0];
            ax = cs * (float)sv[0]; ay = cs * (float)sv[1];
            az = cs * (float)sv[2]; aw = cs * (float)sv[3];
            float bx = 0.f, by = 0.f, bz = 0.f, bw = 0.f;
            int e = beg;
            for (; e + 2 <= end; e += 2) {
                unsigned int w0 = edges[e], w1 = edges[e + 1];
                int s0, s1; float cc0, cc1;
                unpack_edge(w0, s0, cc0); unpack_edge(w1, s1, cc1);
                half4v u0 = *(const half4v*)&h[(size_t)s0 * 64 + c0];
                half4v u1 = *(const half4v*)&h[(size_t)s1 * 64 + c0];
                ax += cc0 * (float)u0[0]; ay += cc0 * (float)u0[1];
                az += cc0 * (float)u0[2]; aw += cc0 * (float)u0[3];
                bx += cc1 * (float)u1[0]; by += cc1 * (float)u1[1];
                bz += cc1 * (float)u1[2]; bw += cc1 * (float)u1[3];
            }
            if (e < end) {
                int s0; float cc0;
                unpack_edge(edges[e], s0, cc0);
                half4v u0 = *(const half4v*)&h[(size_t)s0 * 64 + c0];
                ax += cc0 * (float)u0[0]; ay += cc0 * (float)u0[1];
                az += cc0 * (float)u0[2]; aw += cc0 * (float)u0[3];
            }
            ax = fmaxf(ax + bx + bv.x, 0.f);
            ay = fmaxf(ay + by + bv.y, 0.f);
            az = fmaxf(az + bz + bv.z, 0.f);
            aw = fmaxf(aw + bw + bv.w, 0.f);
        }
        oT[(c0 + 0) * 68 + ni] = ax;
        oT[(c0 + 1) * 68 + ni] = ay;
        oT[(c0 + 2) * 68 + ni] = az;
        oT[(c0 + 3) * 68 + ni] = aw;
    }
    __syncthreads();
    float acc[4][4] = {};
    const float* otp = &oT[ng * 4];
    const float* wsp = &Ws[cg * 4];
    #pragma unroll 2
    for (int k = 0; k < 64; ++k) {
        float4 ov = *(const float4*)&otp[k * 68];
        float4 wv = *(const float4*)&wsp[k * 64];
        #pragma unroll
        for (int i = 0; i < 4; ++i) {
            float o = (&ov.x)[i];
            acc[i][0] += o * wv.x;
            acc[i][1] += o * wv.y;
            acc[i][2] += o * wv.z;
            acc[i][3] += o * wv.w;
        }
    }
    #pragma unroll
    for (int i = 0; i < 4; ++i) {
        float4 p;
        p.x = fmaxf(acc[i][0], 0.f);
        p.y = fmaxf(acc[i][1], 0.f);
        p.z = fmaxf(acc[i][2], 0.f);
        p.w = fmaxf(acc[i][3], 0.f);
        float ss = p.x * p.x + p.y * p.y + p.z * p.z + p.w * p.w;
        #pragma unroll
        for (int off = 1; off < 16; off <<= 1) ss += __shfl_xor(ss, off, 64);
        float norm = sqrtf(ss);
        float sc = 1.0f / fmaxf(norm, 1e-12f);
        int oi = base + ng * 4 + i;
        if (oi < n) {
            int node = order[oi];
            p.x *= sc; p.y *= sc; p.z *= sc; p.w *= sc;
            *(float4*)&P[(size_t)node * 64 + cg * 4] = p;
        }
    }
}

// ---------------- launch ----------------

static inline size_t ws_align(size_t x) { return (x + 255) & ~(size_t)255; }

extern "C" void kernel_launch(void* const* d_in, const int* in_sizes, int n_in,
                              void* d_out, int out_size, void* d_ws, size_t ws_size,
                              hipStream_t stream) {
    const float* x  = (const float*)d_in[0];
    const int*   ei = (const int*)d_in[1];
    const float* W1 = (const float*)d_in[2];
    const float* b1 = (const float*)d_in[3];
    const float* W2 = (const float*)d_in[4];
    const float* b2 = (const float*)d_in[5];
    const float* W3 = (const float*)d_in[6];
    const float* b3 = (const float*)d_in[7];
    const float* Wp = (const float*)d_in[8];

    int n = in_sizes[0] / 128;
    int E = in_sizes[1] / 2;
    const int* src = ei;
    const int* dst = ei + E;

    char* ws = (char*)d_ws;
    size_t off = 0;
    auto alloc = [&](size_t bytes) -> void* {
        void* p = ws + off;
        off = ws_align(off + bytes);
        return p;
    };
    _Float16* bufA = (_Float16*)alloc((size_t)n * 128 * 2);
    _Float16* bufB = (_Float16*)alloc((size_t)n * 128 * 2);
    _Float16* Wt1  = (_Float16*)alloc(128 * 128 * 2);
    _Float16* Wt2  = (_Float16*)alloc(128 * 128 * 2);
    _Float16* Wt3  = (_Float16*)alloc(64 * 128 * 2);
    int*   cnt      = (int*)alloc((size_t)n * 4);
    float* dis      = (float*)alloc((size_t)n * 4);
    int*   row_ptr  = (int*)alloc((size_t)(n + 1) * 4);
    unsigned short* rank = (unsigned short*)alloc((size_t)E * 2);
    unsigned int* edges = (unsigned int*)alloc((size_t)E * 4);
    int*   order    = (int*)alloc((size_t)n * 4);
    int*   hist     = (int*)alloc(NBIN * 4);
    int*   blockSums = (int*)alloc(256);
    (void)off; (void)ws_size;

    int B = (n + 1023) / 1024;
    int wz = 40960 + n;
    cvt_wz<<<(wz + 255) / 256, 256, 0, stream>>>(W1, W2, W3, Wt1, Wt2, Wt3, cnt, hist, n);
    count_rank<<<(E + 255) / 256, 256, 0, stream>>>(dst, E, cnt, rank);
    scanA<<<B, 256, 0, stream>>>(cnt, row_ptr, blockSums, dis, hist, n);
    scanC<<<B, 256, 0, stream>>>(row_ptr, blockSums, n, E, B);
    scan_hist<<<1, 256, 0, stream>>>(hist);
    scatter_order<<<(n + 255) / 256, 256, 0, stream>>>(cnt, hist, order, n);
    fill_nr<<<(E + 255) / 256, 256, 0, stream>>>(src, dst, rank, E, row_ptr, dis, edges);

    int gblocks = (n + 63) / 64;
    int fblocks = (n + 15) / 16;
    int pblocks = (n + 63) / 64;
    float* outp = (float*)d_out;

    gemm_mfma<128, true><<<gblocks, 256, 0, stream>>>(x, Wt1, bufA, n);
    agg_gemm<128><<<fblocks, 1024, 0, stream>>>((const __half2*)bufA, row_ptr, edges, dis, b1,
                                                Wt2, order, bufB, n);
    agg_gemm<64><<<fblocks, 1024, 0, stream>>>((const __half2*)bufB, row_ptr, edges, dis, b2,
                                               Wt3, order, bufA, n);
    agg_proj<<<pblocks, 256, 0, stream>>>(bufA, row_ptr, edges, dis, b3, Wp, order, outp, n);
}

// Round 14
// 245.408 us; speedup vs baseline: 2.0518x; 2.0518x over previous
//
#include <hip/hip_runtime.h>
#include <hip/hip_fp16.h>

typedef _Float16 half8v __attribute__((ext_vector_type(8)));
typedef _Float16 half4v __attribute__((ext_vector_type(4)));
typedef _Float16 half2v __attribute__((ext_vector_type(2)));
typedef float f32x4 __attribute__((ext_vector_type(4)));

#define NBIN 1024

// ---------------- fused: transpose-convert W1/W2/W3 to fp16 Wt[N][128] + zero cnt/hist ----------------

__global__ void cvt_wz(const float* __restrict__ W1, const float* __restrict__ W2,
                       const float* __restrict__ W3,
                       _Float16* __restrict__ Wt1, _Float16* __restrict__ Wt2,
                       _Float16* __restrict__ Wt3,
                       int* __restrict__ cnt, int* __restrict__ hist, int n) {
    int i = blockIdx.x * blockDim.x + threadIdx.x;
    if (i < 16384) {
        int nn = i >> 7, kk = i & 127;
        Wt1[i] = (_Float16)W1[kk * 128 + nn];
    } else if (i < 32768) {
        int j = i - 16384; int nn = j >> 7, kk = j & 127;
        Wt2[j] = (_Float16)W2[kk * 128 + nn];
    } else if (i < 40960) {
        int j = i - 32768; int nn = j >> 7, kk = j & 127;
        Wt3[j] = (_Float16)W3[kk * 64 + nn];
    }
    if (i < NBIN) hist[i] = 0;
    int z = i - 40960;
    if (z >= 0 && z < n) cnt[z] = 0;
}

// ---------------- degree count; atomic's return value IS the edge's rank in its row ----------------

__global__ void count_rank(const int* __restrict__ dst, int E, int* __restrict__ cnt,
                           unsigned short* __restrict__ rank) {
    int e = blockIdx.x * blockDim.x + threadIdx.x;
    if (e < E) rank[e] = (unsigned short)atomicAdd(&cnt[dst[e]], 1);
}

// scanA: block-local exclusive scan of cnt + dis = rsqrt(deg+1) + degree histogram
__global__ __launch_bounds__(256) void scanA(const int* __restrict__ cnt,
                                             int* __restrict__ row_ptr,
                                             int* __restrict__ blockSums,
                                             float* __restrict__ dis,
                                             int* __restrict__ hist, int n) {
    __shared__ int s[256];
    __shared__ int lh[NBIN];
    int t = threadIdx.x;
    #pragma unroll
    for (int j = t; j < NBIN; j += 256) lh[j] = 0;
    __syncthreads();
    int base = blockIdx.x * 1024 + t * 4;
    int v0 = (base + 0 < n) ? cnt[base + 0] : 0;
    int v1 = (base + 1 < n) ? cnt[base + 1] : 0;
    int v2 = (base + 2 < n) ? cnt[base + 2] : 0;
    int v3 = (base + 3 < n) ? cnt[base + 3] : 0;
    if (base + 0 < n) { dis[base + 0] = rsqrtf((float)(v0 + 1)); atomicAdd(&lh[min(v0, NBIN - 1)], 1); }
    if (base + 1 < n) { dis[base + 1] = rsqrtf((float)(v1 + 1)); atomicAdd(&lh[min(v1, NBIN - 1)], 1); }
    if (base + 2 < n) { dis[base + 2] = rsqrtf((float)(v2 + 1)); atomicAdd(&lh[min(v2, NBIN - 1)], 1); }
    if (base + 3 < n) { dis[base + 3] = rsqrtf((float)(v3 + 1)); atomicAdd(&lh[min(v3, NBIN - 1)], 1); }
    int tsum = v0 + v1 + v2 + v3;
    s[t] = tsum;
    __syncthreads();
    for (int off = 1; off < 256; off <<= 1) {
        int u = (t >= off) ? s[t - off] : 0;
        __syncthreads();
        s[t] += u;
        __syncthreads();
    }
    int excl = s[t] - tsum;
    if (base + 0 < n) row_ptr[base + 0] = excl;
    if (base + 1 < n) row_ptr[base + 1] = excl + v0;
    if (base + 2 < n) row_ptr[base + 2] = excl + v0 + v1;
    if (base + 3 < n) row_ptr[base + 3] = excl + v0 + v1 + v2;
    if (t == 255) blockSums[blockIdx.x] = s[255];
    __syncthreads();
    #pragma unroll
    for (int j = t; j < NBIN; j += 256)
        if (lh[j] > 0) atomicAdd(&hist[j], lh[j]);
}

// scanC with inlined block-sum scan (B <= 64 blocks)
__global__ __launch_bounds__(256) void scanC(int* __restrict__ row_ptr,
                                             const int* __restrict__ blockSums,
                                             int n, int E, int B) {
    __shared__ int soff;
    int t = threadIdx.x;
    if (t < 64) {
        int v = (t < B) ? blockSums[t] : 0;
        int orig = v;
        for (int off = 1; off < 64; off <<= 1) {
            int u = __shfl_up(v, off, 64);
            if (t >= off) v += u;
        }
        if (t == (int)blockIdx.x) soff = v - orig;
    }
    __syncthreads();
    int off = soff;
    int base = blockIdx.x * 1024 + t * 4;
    #pragma unroll
    for (int j = 0; j < 4; ++j)
        if (base + j < n) row_ptr[base + j] += off;
    if (blockIdx.x == 0 && t == 0) row_ptr[n] = E;
}

// in-place exclusive scan of the 1024-bin degree histogram (single block)
__global__ __launch_bounds__(256) void scan_hist(int* __restrict__ hist) {
    __shared__ int s[256];
    int t = threadIdx.x;
    int v0 = hist[t * 4], v1 = hist[t * 4 + 1], v2 = hist[t * 4 + 2], v3 = hist[t * 4 + 3];
    int tsum = v0 + v1 + v2 + v3;
    s[t] = tsum;
    __syncthreads();
    for (int off = 1; off < 256; off <<= 1) {
        int u = (t >= off) ? s[t - off] : 0;
        __syncthreads();
        s[t] += u;
        __syncthreads();
    }
    int excl = s[t] - tsum;
    hist[t * 4 + 0] = excl;
    hist[t * 4 + 1] = excl + v0;
    hist[t * 4 + 2] = excl + v0 + v1;
    hist[t * 4 + 3] = excl + v0 + v1 + v2;
}

// two-level counting-sort scatter: LDS local hist -> one global atomic per (block,bin)
__global__ __launch_bounds__(256) void scatter_order(const int* __restrict__ cnt,
                                                     int* __restrict__ histoff,
                                                     int* __restrict__ order, int n) {
    __shared__ int lh[NBIN];
    __shared__ int gbase[NBIN];
    int t = threadIdx.x;
    #pragma unroll
    for (int j = t; j < NBIN; j += 256) lh[j] = 0;
    __syncthreads();
    int i = blockIdx.x * 256 + t;
    int bin = -1, lrank = 0;
    if (i < n) {
        bin = min(cnt[i], NBIN - 1);
        lrank = atomicAdd(&lh[bin], 1);
    }
    __syncthreads();
    #pragma unroll
    for (int j = t; j < NBIN; j += 256)
        if (lh[j] > 0) gbase[j] = atomicAdd(&histoff[j], lh[j]);
    __syncthreads();
    if (i < n) order[gbase[bin] + lrank] = i;
}

// atomic-free CSR fill: slot = row_ptr[d] + rank[e]
__global__ void fill_nr(const int* __restrict__ src, const int* __restrict__ dst,
                        const unsigned short* __restrict__ rank, int E,
                        const int* __restrict__ row_ptr, const float* __restrict__ dis,
                        unsigned int* __restrict__ edges) {
    int e = blockIdx.x * blockDim.x + threadIdx.x;
    if (e >= E) return;
    int d = dst[e], s = src[e];
    int slot = row_ptr[d] + (int)rank[e];
    float coef = dis[s] * dis[d];
    edges[slot] = (unsigned)s |
                  ((unsigned)__half_as_ushort(__float2half_rn(coef)) << 16);
}

__device__ __forceinline__ void unpack_edge(unsigned int w, int& s, float& c) {
    s = (int)(w & 0xffffu);
    c = __half2float(__ushort_as_half((unsigned short)(w >> 16)));
}

// ---------------- MFMA GEMM layer 1: Y[M,128](fp16) = f32 x @ Wt1[128][128] ----------------

template <int N, bool F32IN>
__global__ __launch_bounds__(256) void gemm_mfma(const void* __restrict__ Xin,
                                                 const _Float16* __restrict__ Wt,
                                                 _Float16* __restrict__ Y, int M) {
    constexpr int NT = N / 16;
    int wave = threadIdx.x >> 6;
    int lane = threadIdx.x & 63;
    int m0 = blockIdx.x * 64 + wave * 16;
    int r = lane & 15;
    int kb = lane >> 4;
    int ar = m0 + r; if (ar >= M) ar = M - 1;
    f32x4 acc[NT] = {};
    #pragma unroll
    for (int kk = 0; kk < 128; kk += 32) {
        half8v a;
        if constexpr (F32IN) {
            const float* arow = (const float*)Xin + (size_t)ar * 128 + kb * 8 + kk;
            float4 f0 = *(const float4*)arow;
            float4 f1 = *(const float4*)(arow + 4);
            a = (half8v){(_Float16)f0.x, (_Float16)f0.y, (_Float16)f0.z, (_Float16)f0.w,
                         (_Float16)f1.x, (_Float16)f1.y, (_Float16)f1.z, (_Float16)f1.w};
        } else {
            a = *(const half8v*)((const _Float16*)Xin + (size_t)ar * 128 + kb * 8 + kk);
        }
        #pragma unroll
        for (int c = 0; c < NT; ++c) {
            half8v b = *(const half8v*)(Wt + (size_t)(c * 16 + r) * 128 + kk + kb * 8);
            acc[c] = __builtin_amdgcn_mfma_f32_16x16x32_f16(a, b, acc[c], 0, 0, 0);
        }
    }
    #pragma unroll
    for (int j = 0; j < 4; ++j) {
        int row = m0 + kb * 4 + j;
        if (row < M) {
            #pragma unroll
            for (int c = 0; c < NT; ++c)
                Y[(size_t)row * N + c * 16 + r] = (_Float16)acc[c][j];
        }
    }
}

// ---------------- FUSED agg(D=128) + GEMM over degree-sorted nodes ----------------
// 1024 threads = 16 waves; one node per wave, node = order[blockIdx*16 + wave] so all
// 16 nodes in a block have ~equal degree (barrier waits ~nothing). As[16][136] fp16;
// wave w < NOUT/16 then computes col-tile w of the 16x128 @ 128xNOUT product.

template <int NOUT>
__global__ __launch_bounds__(1024) void agg_gemm(const __half2* __restrict__ hp,
                                                 const int* __restrict__ row_ptr,
                                                 const unsigned int* __restrict__ edges,
                                                 const float* __restrict__ dis,
                                                 const float* __restrict__ bias,
                                                 const _Float16* __restrict__ Wt,
                                                 const int* __restrict__ order,
                                                 _Float16* __restrict__ Y, int n) {
    __shared__ _Float16 As[16][136];
    __shared__ int nid[16];
    int t = threadIdx.x;
    int wave = t >> 6;
    int lane = t & 63;
    int m0 = blockIdx.x * 16;
    int node = (m0 + wave < n) ? order[m0 + wave] : -1;
    if (lane == 0) nid[wave] = node;
    float ox = 0.f, oy = 0.f;
    if (node >= 0) {
        int beg = row_ptr[node], end = row_ptr[node + 1];
        float di = dis[node];
        float cs = di * di;
        float2 sv = __half22float2(hp[(size_t)node * 64 + lane]);
        float2 a0 = {cs * sv.x, cs * sv.y};
        float2 a1 = {0.f, 0.f}, a2 = {0.f, 0.f}, a3 = {0.f, 0.f};
        int e = beg;
        for (; e + 4 <= end; e += 4) {
            unsigned int w0 = edges[e], w1 = edges[e + 1], w2 = edges[e + 2], w3 = edges[e + 3];
            int s0, s1, s2, s3; float c0, c1, c2, c3;
            unpack_edge(w0, s0, c0); unpack_edge(w1, s1, c1);
            unpack_edge(w2, s2, c2); unpack_edge(w3, s3, c3);
            float2 u0 = __half22float2(hp[(size_t)s0 * 64 + lane]);
            float2 u1 = __half22float2(hp[(size_t)s1 * 64 + lane]);
            float2 u2 = __half22float2(hp[(size_t)s2 * 64 + lane]);
            float2 u3 = __half22float2(hp[(size_t)s3 * 64 + lane]);
            a0.x += c0 * u0.x; a0.y += c0 * u0.y;
            a1.x += c1 * u1.x; a1.y += c1 * u1.y;
            a2.x += c2 * u2.x; a2.y += c2 * u2.y;
            a3.x += c3 * u3.x; a3.y += c3 * u3.y;
        }
        for (; e < end; ++e) {
            int s0; float c0;
            unpack_edge(edges[e], s0, c0);
            float2 u0 = __half22float2(hp[(size_t)s0 * 64 + lane]);
            a0.x += c0 * u0.x; a0.y += c0 * u0.y;
        }
        float2 bv = ((const float2*)bias)[lane];
        ox = fmaxf(a0.x + a1.x + a2.x + a3.x + bv.x, 0.f);
        oy = fmaxf(a0.y + a1.y + a2.y + a3.y + bv.y, 0.f);
    }
    *(half2v*)&As[wave][2 * lane] = (half2v){(_Float16)ox, (_Float16)oy};
    __syncthreads();
    constexpr int CT = NOUT / 16;  // 8 or 4 col tiles
    if (wave < CT) {
        int r = lane & 15;
        int kb = lane >> 4;
        f32x4 acc = {};
        #pragma unroll
        for (int kk = 0; kk < 128; kk += 32) {
            half8v a = *(const half8v*)&As[r][kb * 8 + kk];
            half8v b = *(const half8v*)(Wt + (size_t)(wave * 16 + r) * 128 + kk + kb * 8);
            acc = __builtin_amdgcn_mfma_f32_16x16x32_f16(a, b, acc, 0, 0, 0);
        }
        #pragma unroll
        for (int j = 0; j < 4; ++j) {
            int row = nid[kb * 4 + j];
            if (row >= 0)
                Y[(size_t)row * NOUT + wave * 16 + r] = (_Float16)acc[j];
        }
    }
}

// ---------------- FUSED agg(D=64) + projection + relu + row-normalize (degree-sorted) ----------------

__global__ __launch_bounds__(256) void agg_proj(const _Float16* __restrict__ h,
                                                const int* __restrict__ row_ptr,
                                                const unsigned int* __restrict__ edges,
                                                const float* __restrict__ dis,
                                                const float* __restrict__ b3,
                                                const float* __restrict__ Wp,
                                                const int* __restrict__ order,
                                                float* __restrict__ P, int n) {
    __shared__ float oT[64 * 68];
    __shared__ float Ws[64 * 64];
    int t = threadIdx.x;
    int base = blockIdx.x * 64;
    for (int j = t * 4; j < 4096; j += 1024)
        *(float4*)&Ws[j] = *(const float4*)&Wp[j];
    int cg = t & 15;   // col group: dims 4*cg..+3
    int ng = t >> 4;   // node-in-pass 0..15
    int c0 = cg * 4;
    float4 bv = *(const float4*)&b3[c0];
    #pragma unroll
    for (int pass = 0; pass < 4; ++pass) {
        int ni = pass * 16 + ng;
        int node = (base + ni < n) ? order[base + ni] : -1;
        float ax = 0.f, ay = 0.f, az = 0.f, aw = 0.f;
        if (node >= 0) {
            int beg = row_ptr[node], end = row_ptr[node + 1];
            float di = dis[node];
            float cs = di * di;
            half4v sv = *(const half4v*)&h[(size_t)node * 64 + c0];
            ax = cs * (float)sv[0]; ay = cs * (float)sv[1];
            az = cs * (float)sv[2]; aw = cs * (float)sv[3];
            float bx = 0.f, by = 0.f, bz = 0.f, bw = 0.f;
            int e = beg;
            for (; e + 2 <= end; e += 2) {
                unsigned int w0 = edges[e], w1 = edges[e + 1];
                int s0, s1; float cc0, cc1;
                unpack_edge(w0, s0, cc0); unpack_edge(w1, s1, cc1);
                half4v u0 = *(const half4v*)&h[(size_t)s0 * 64 + c0];
                half4v u1 = *(const half4v*)&h[(size_t)s1 * 64 + c0];
                ax += cc0 * (float)u0[0]; ay += cc0 * (float)u0[1];
                az += cc0 * (float)u0[2]; aw += cc0 * (float)u0[3];
                bx += cc1 * (float)u1[0]; by += cc1 * (float)u1[1];
                bz += cc1 * (float)u1[2]; bw += cc1 * (float)u1[3];
            }
            if (e < end) {
                int s0; float cc0;
                unpack_edge(edges[e], s0, cc0);
                half4v u0 = *(const half4v*)&h[(size_t)s0 * 64 + c0];
                ax += cc0 * (float)u0[0]; ay += cc0 * (float)u0[1];
                az += cc0 * (float)u0[2]; aw += cc0 * (float)u0[3];
            }
            ax = fmaxf(ax + bx + bv.x, 0.f);
            ay = fmaxf(ay + by + bv.y, 0.f);
            az = fmaxf(az + bz + bv.z, 0.f);
            aw = fmaxf(aw + bw + bv.w, 0.f);
        }
        oT[(c0 + 0) * 68 + ni] = ax;
        oT[(c0 + 1) * 68 + ni] = ay;
        oT[(c0 + 2) * 68 + ni] = az;
        oT[(c0 + 3) * 68 + ni] = aw;
    }
    __syncthreads();
    float acc[4][4] = {};
    const float* otp = &oT[ng * 4];
    const float* wsp = &Ws[cg * 4];
    #pragma unroll 2
    for (int k = 0; k < 64; ++k) {
        float4 ov = *(const float4*)&otp[k * 68];
        float4 wv = *(const float4*)&wsp[k * 64];
        #pragma unroll
        for (int i = 0; i < 4; ++i) {
            float o = (&ov.x)[i];
            acc[i][0] += o * wv.x;
            acc[i][1] += o * wv.y;
            acc[i][2] += o * wv.z;
            acc[i][3] += o * wv.w;
        }
    }
    #pragma unroll
    for (int i = 0; i < 4; ++i) {
        float4 p;
        p.x = fmaxf(acc[i][0], 0.f);
        p.y = fmaxf(acc[i][1], 0.f);
        p.z = fmaxf(acc[i][2], 0.f);
        p.w = fmaxf(acc[i][3], 0.f);
        float ss = p.x * p.x + p.y * p.y + p.z * p.z + p.w * p.w;
        #pragma unroll
        for (int off = 1; off < 16; off <<= 1) ss += __shfl_xor(ss, off, 64);
        float norm = sqrtf(ss);
        float sc = 1.0f / fmaxf(norm, 1e-12f);
        int oi = base + ng * 4 + i;
        if (oi < n) {
            int node = order[oi];
            p.x *= sc; p.y *= sc; p.z *= sc; p.w *= sc;
            *(float4*)&P[(size_t)node * 64 + cg * 4] = p;
        }
    }
}

// ---------------- launch ----------------

static inline size_t ws_align(size_t x) { return (x + 255) & ~(size_t)255; }

extern "C" void kernel_launch(void* const* d_in, const int* in_sizes, int n_in,
                              void* d_out, int out_size, void* d_ws, size_t ws_size,
                              hipStream_t stream) {
    const float* x  = (const float*)d_in[0];
    const int*   ei = (const int*)d_in[1];
    const float* W1 = (const float*)d_in[2];
    const float* b1 = (const float*)d_in[3];
    const float* W2 = (const float*)d_in[4];
    const float* b2 = (const float*)d_in[5];
    const float* W3 = (const float*)d_in[6];
    const float* b3 = (const float*)d_in[7];
    const float* Wp = (const float*)d_in[8];

    int n = in_sizes[0] / 128;
    int E = in_sizes[1] / 2;
    const int* src = ei;
    const int* dst = ei + E;

    char* ws = (char*)d_ws;
    size_t off = 0;
    auto alloc = [&](size_t bytes) -> void* {
        void* p = ws + off;
        off = ws_align(off + bytes);
        return p;
    };
    _Float16* bufA = (_Float16*)alloc((size_t)n * 128 * 2);
    _Float16* bufB = (_Float16*)alloc((size_t)n * 128 * 2);
    _Float16* Wt1  = (_Float16*)alloc(128 * 128 * 2);
    _Float16* Wt2  = (_Float16*)alloc(128 * 128 * 2);
    _Float16* Wt3  = (_Float16*)alloc(64 * 128 * 2);
    int*   cnt      = (int*)alloc((size_t)n * 4);
    float* dis      = (float*)alloc((size_t)n * 4);
    int*   row_ptr  = (int*)alloc((size_t)(n + 1) * 4);
    unsigned short* rank = (unsigned short*)alloc((size_t)E * 2);
    unsigned int* edges = (unsigned int*)alloc((size_t)E * 4);
    int*   order    = (int*)alloc((size_t)n * 4);
    int*   hist     = (int*)alloc(NBIN * 4);
    int*   blockSums = (int*)alloc(256);
    (void)off; (void)ws_size;

    int B = (n + 1023) / 1024;
    int wz = 40960 + n;
    cvt_wz<<<(wz + 255) / 256, 256, 0, stream>>>(W1, W2, W3, Wt1, Wt2, Wt3, cnt, hist, n);
    count_rank<<<(E + 255) / 256, 256, 0, stream>>>(dst, E, cnt, rank);
    scanA<<<B, 256, 0, stream>>>(cnt, row_ptr, blockSums, dis, hist, n);
    scanC<<<B, 256, 0, stream>>>(row_ptr, blockSums, n, E, B);
    scan_hist<<<1, 256, 0, stream>>>(hist);
    scatter_order<<<(n + 255) / 256, 256, 0, stream>>>(cnt, hist, order, n);
    fill_nr<<<(E + 255) / 256, 256, 0, stream>>>(src, dst, rank, E, row_ptr, dis, edges);

    int gblocks = (n + 63) / 64;
    int fblocks = (n + 15) / 16;
    int pblocks = (n + 63) / 64;
    float* outp = (float*)d_out;

    gemm_mfma<128, true><<<gblocks, 256, 0, stream>>>(x, Wt1, bufA, n);
    agg_gemm<128><<<fblocks, 1024, 0, stream>>>((const __half2*)bufA, row_ptr, edges, dis, b1,
                                                Wt2, order, bufB, n);
    agg_gemm<64><<<fblocks, 1024, 0, stream>>>((const __half2*)bufB, row_ptr, edges, dis, b2,
                                               Wt3, order, bufA, n);
    agg_proj<<<pblocks, 256, 0, stream>>>(bufA, row_ptr, edges, dis, b3, Wp, order, outp, n);
}

// Round 15
// 219.812 us; speedup vs baseline: 2.2907x; 1.1164x over previous
//
#include <hip/hip_runtime.h>
#include <hip/hip_fp16.h>

typedef _Float16 half8v __attribute__((ext_vector_type(8)));
typedef _Float16 half4v __attribute__((ext_vector_type(4)));
typedef _Float16 half2v __attribute__((ext_vector_type(2)));
typedef float f32x4 __attribute__((ext_vector_type(4)));

// ---------------- fused: transpose-convert W1/W2/W3 to fp16 Wt[N][128] + zero cnt ----------------

__global__ void cvt_wz(const float* __restrict__ W1, const float* __restrict__ W2,
                       const float* __restrict__ W3,
                       _Float16* __restrict__ Wt1, _Float16* __restrict__ Wt2,
                       _Float16* __restrict__ Wt3,
                       int* __restrict__ cnt, int n) {
    int i = blockIdx.x * blockDim.x + threadIdx.x;
    if (i < 16384) {
        int nn = i >> 7, kk = i & 127;
        Wt1[i] = (_Float16)W1[kk * 128 + nn];
    } else if (i < 32768) {
        int j = i - 16384; int nn = j >> 7, kk = j & 127;
        Wt2[j] = (_Float16)W2[kk * 128 + nn];
    } else if (i < 40960) {
        int j = i - 32768; int nn = j >> 7, kk = j & 127;
        Wt3[j] = (_Float16)W3[kk * 64 + nn];
    }
    int z = i - 40960;
    if (z >= 0 && z < n) cnt[z] = 0;
}

// ---------------- degree count; atomic's return value IS the edge's rank in its row ----------------

__global__ void count_rank(const int* __restrict__ dst, int E, int* __restrict__ cnt,
                           unsigned short* __restrict__ rank) {
    int e = blockIdx.x * blockDim.x + threadIdx.x;
    if (e < E) rank[e] = (unsigned short)atomicAdd(&cnt[dst[e]], 1);
}

// scanA: block-local exclusive scan of cnt + dis = rsqrt(deg+1)
__global__ __launch_bounds__(256) void scanA(const int* __restrict__ cnt,
                                             int* __restrict__ row_ptr,
                                             int* __restrict__ blockSums,
                                             float* __restrict__ dis, int n) {
    __shared__ int s[256];
    int t = threadIdx.x;
    int base = blockIdx.x * 1024 + t * 4;
    int v0 = (base + 0 < n) ? cnt[base + 0] : 0;
    int v1 = (base + 1 < n) ? cnt[base + 1] : 0;
    int v2 = (base + 2 < n) ? cnt[base + 2] : 0;
    int v3 = (base + 3 < n) ? cnt[base + 3] : 0;
    if (base + 0 < n) dis[base + 0] = rsqrtf((float)(v0 + 1));
    if (base + 1 < n) dis[base + 1] = rsqrtf((float)(v1 + 1));
    if (base + 2 < n) dis[base + 2] = rsqrtf((float)(v2 + 1));
    if (base + 3 < n) dis[base + 3] = rsqrtf((float)(v3 + 1));
    int tsum = v0 + v1 + v2 + v3;
    s[t] = tsum;
    __syncthreads();
    for (int off = 1; off < 256; off <<= 1) {
        int u = (t >= off) ? s[t - off] : 0;
        __syncthreads();
        s[t] += u;
        __syncthreads();
    }
    int excl = s[t] - tsum;
    if (base + 0 < n) row_ptr[base + 0] = excl;
    if (base + 1 < n) row_ptr[base + 1] = excl + v0;
    if (base + 2 < n) row_ptr[base + 2] = excl + v0 + v1;
    if (base + 3 < n) row_ptr[base + 3] = excl + v0 + v1 + v2;
    if (t == 255) blockSums[blockIdx.x] = s[255];
}

// scanC with inlined block-sum scan (B <= 64 blocks)
__global__ __launch_bounds__(256) void scanC(int* __restrict__ row_ptr,
                                             const int* __restrict__ blockSums,
                                             int n, int E, int B) {
    __shared__ int soff;
    int t = threadIdx.x;
    if (t < 64) {
        int v = (t < B) ? blockSums[t] : 0;
        int orig = v;
        for (int off = 1; off < 64; off <<= 1) {
            int u = __shfl_up(v, off, 64);
            if (t >= off) v += u;
        }
        if (t == (int)blockIdx.x) soff = v - orig;
    }
    __syncthreads();
    int off = soff;
    int base = blockIdx.x * 1024 + t * 4;
    #pragma unroll
    for (int j = 0; j < 4; ++j)
        if (base + j < n) row_ptr[base + j] += off;
    if (blockIdx.x == 0 && t == 0) row_ptr[n] = E;
}

// atomic-free CSR fill: slot = row_ptr[d] + rank[e]
__global__ void fill_nr(const int* __restrict__ src, const int* __restrict__ dst,
                        const unsigned short* __restrict__ rank, int E,
                        const int* __restrict__ row_ptr, const float* __restrict__ dis,
                        unsigned int* __restrict__ edges) {
    int e = blockIdx.x * blockDim.x + threadIdx.x;
    if (e >= E) return;
    int d = dst[e], s = src[e];
    int slot = row_ptr[d] + (int)rank[e];
    float coef = dis[s] * dis[d];
    edges[slot] = (unsigned)s |
                  ((unsigned)__half_as_ushort(__float2half_rn(coef)) << 16);
}

__device__ __forceinline__ void unpack_edge(unsigned int w, int& s, float& c) {
    s = (int)(w & 0xffffu);
    c = __half2float(__ushort_as_half((unsigned short)(w >> 16)));
}

// ---------------- MFMA GEMM layer 1: Y[M,128](fp16) = f32 x @ Wt1[128][128] ----------------

template <int N, bool F32IN>
__global__ __launch_bounds__(256) void gemm_mfma(const void* __restrict__ Xin,
                                                 const _Float16* __restrict__ Wt,
                                                 _Float16* __restrict__ Y, int M) {
    constexpr int NT = N / 16;
    int wave = threadIdx.x >> 6;
    int lane = threadIdx.x & 63;
    int m0 = blockIdx.x * 64 + wave * 16;
    int r = lane & 15;
    int kb = lane >> 4;
    int ar = m0 + r; if (ar >= M) ar = M - 1;
    f32x4 acc[NT] = {};
    #pragma unroll
    for (int kk = 0; kk < 128; kk += 32) {
        half8v a;
        if constexpr (F32IN) {
            const float* arow = (const float*)Xin + (size_t)ar * 128 + kb * 8 + kk;
            float4 f0 = *(const float4*)arow;
            float4 f1 = *(const float4*)(arow + 4);
            a = (half8v){(_Float16)f0.x, (_Float16)f0.y, (_Float16)f0.z, (_Float16)f0.w,
                         (_Float16)f1.x, (_Float16)f1.y, (_Float16)f1.z, (_Float16)f1.w};
        } else {
            a = *(const half8v*)((const _Float16*)Xin + (size_t)ar * 128 + kb * 8 + kk);
        }
        #pragma unroll
        for (int c = 0; c < NT; ++c) {
            half8v b = *(const half8v*)(Wt + (size_t)(c * 16 + r) * 128 + kk + kb * 8);
            acc[c] = __builtin_amdgcn_mfma_f32_16x16x32_f16(a, b, acc[c], 0, 0, 0);
        }
    }
    #pragma unroll
    for (int j = 0; j < 4; ++j) {
        int row = m0 + kb * 4 + j;
        if (row < M) {
            #pragma unroll
            for (int c = 0; c < NT; ++c)
                Y[(size_t)row * N + c * 16 + r] = (_Float16)acc[c][j];
        }
    }
}

// ---------------- FUSED agg(D=128) + GEMM with QUAD-EDGE gather ----------------
// 1024 thr = 16 waves, one node per wave. Lane layout: grp = lane>>4 picks one of 4
// edges, sub = lane&15 picks 16B of the 256B fp16 row -> ONE dwordx4 load fetches 4
// edges' full rows (4x fewer gather instructions). Cross-group combine: 2 shfl_xor.
// Then As[16][136] + per-wave 16-col MFMA tile as before.

template <int NOUT>
__global__ __launch_bounds__(1024) void agg_gemm(const _Float16* __restrict__ h,
                                                 const int* __restrict__ row_ptr,
                                                 const unsigned int* __restrict__ edges,
                                                 const float* __restrict__ dis,
                                                 const float* __restrict__ bias,
                                                 const _Float16* __restrict__ Wt,
                                                 _Float16* __restrict__ Y, int n) {
    __shared__ _Float16 As[16][136];
    int t = threadIdx.x;
    int wave = t >> 6;
    int lane = t & 63;
    int m0 = blockIdx.x * 16;
    int node = m0 + wave;
    int grp = lane >> 4;   // edge slot 0..3
    int sub = lane & 15;   // dim quad: dims sub*8 .. sub*8+7
    if (node < n) {
        int beg = row_ptr[node], end = row_ptr[node + 1];
        float di = dis[node];
        float cs = di * di;
        float acc[8] = {0.f, 0.f, 0.f, 0.f, 0.f, 0.f, 0.f, 0.f};
        if (grp == 0) {
            half8v sv = *(const half8v*)(h + (size_t)node * 128 + sub * 8);
            #pragma unroll
            for (int j = 0; j < 8; ++j) acc[j] = cs * (float)sv[j];
        }
        int e = beg;
        for (; e + 8 <= end; e += 8) {
            unsigned int w0 = edges[e + grp];
            unsigned int w1 = edges[e + 4 + grp];
            int s0, s1; float c0, c1;
            unpack_edge(w0, s0, c0); unpack_edge(w1, s1, c1);
            half8v u0 = *(const half8v*)(h + (size_t)s0 * 128 + sub * 8);
            half8v u1 = *(const half8v*)(h + (size_t)s1 * 128 + sub * 8);
            #pragma unroll
            for (int j = 0; j < 8; ++j) acc[j] += c0 * (float)u0[j];
            #pragma unroll
            for (int j = 0; j < 8; ++j) acc[j] += c1 * (float)u1[j];
        }
        for (; e < end; e += 4) {
            int ee = e + grp;
            float c0 = 0.f; int s0 = node;
            if (ee < end) { unsigned int w = edges[ee]; unpack_edge(w, s0, c0); }
            half8v u0 = *(const half8v*)(h + (size_t)s0 * 128 + sub * 8);
            #pragma unroll
            for (int j = 0; j < 8; ++j) acc[j] += c0 * (float)u0[j];
        }
        // combine the 4 edge-groups (lanes xor 16, xor 32 hold same sub)
        #pragma unroll
        for (int j = 0; j < 8; ++j) {
            acc[j] += __shfl_xor(acc[j], 16, 64);
            acc[j] += __shfl_xor(acc[j], 32, 64);
        }
        if (grp == 0) {
            float4 b0 = *(const float4*)&bias[sub * 8];
            float4 b1 = *(const float4*)&bias[sub * 8 + 4];
            half8v o;
            o[0] = (_Float16)fmaxf(acc[0] + b0.x, 0.f);
            o[1] = (_Float16)fmaxf(acc[1] + b0.y, 0.f);
            o[2] = (_Float16)fmaxf(acc[2] + b0.z, 0.f);
            o[3] = (_Float16)fmaxf(acc[3] + b0.w, 0.f);
            o[4] = (_Float16)fmaxf(acc[4] + b1.x, 0.f);
            o[5] = (_Float16)fmaxf(acc[5] + b1.y, 0.f);
            o[6] = (_Float16)fmaxf(acc[6] + b1.z, 0.f);
            o[7] = (_Float16)fmaxf(acc[7] + b1.w, 0.f);
            *(half8v*)&As[wave][sub * 8] = o;
        }
    } else if (lane < 16) {
        half8v z = {};
        *(half8v*)&As[wave][sub * 8] = z;
    }
    __syncthreads();
    constexpr int CT = NOUT / 16;  // 8 or 4 col tiles
    if (wave < CT) {
        int r = lane & 15;
        int kb = lane >> 4;
        f32x4 acc = {};
        #pragma unroll
        for (int kk = 0; kk < 128; kk += 32) {
            half8v a = *(const half8v*)&As[r][kb * 8 + kk];
            half8v b = *(const half8v*)(Wt + (size_t)(wave * 16 + r) * 128 + kk + kb * 8);
            acc = __builtin_amdgcn_mfma_f32_16x16x32_f16(a, b, acc, 0, 0, 0);
        }
        #pragma unroll
        for (int j = 0; j < 4; ++j) {
            int row = m0 + kb * 4 + j;
            if (row < n)
                Y[(size_t)row * NOUT + wave * 16 + r] = (_Float16)acc[j];
        }
    }
}

// ---------------- FUSED agg(D=64) + projection + relu + row-normalize ----------------
// block = 64 nodes. 16 threads/node x half4 (already one 128B row per quarter-wave
// instruction = 4 edge-rows per wave instruction). Writes transposed oT then proj.

__global__ __launch_bounds__(256) void agg_proj(const _Float16* __restrict__ h,
                                                const int* __restrict__ row_ptr,
                                                const unsigned int* __restrict__ edges,
                                                const float* __restrict__ dis,
                                                const float* __restrict__ b3,
                                                const float* __restrict__ Wp,
                                                float* __restrict__ P, int n) {
    __shared__ float oT[64 * 68];
    __shared__ float Ws[64 * 64];
    int t = threadIdx.x;
    int base = blockIdx.x * 64;
    for (int j = t * 4; j < 4096; j += 1024)
        *(float4*)&Ws[j] = *(const float4*)&Wp[j];
    int cg = t & 15;   // col group: dims 4*cg..+3
    int ng = t >> 4;   // node-in-pass 0..15
    int c0 = cg * 4;
    float4 bv = *(const float4*)&b3[c0];
    #pragma unroll
    for (int pass = 0; pass < 4; ++pass) {
        int ni = pass * 16 + ng;
        int node = base + ni;
        float ax = 0.f, ay = 0.f, az = 0.f, aw = 0.f;
        if (node < n) {
            int beg = row_ptr[node], end = row_ptr[node + 1];
            float di = dis[node];
            float cs = di * di;
            half4v sv = *(const half4v*)&h[(size_t)node * 64 + c0];
            ax = cs * (float)sv[0]; ay = cs * (float)sv[1];
            az = cs * (float)sv[2]; aw = cs * (float)sv[3];
            float bx = 0.f, by = 0.f, bz = 0.f, bw = 0.f;
            int e = beg;
            for (; e + 2 <= end; e += 2) {
                unsigned int w0 = edges[e], w1 = edges[e + 1];
                int s0, s1; float cc0, cc1;
                unpack_edge(w0, s0, cc0); unpack_edge(w1, s1, cc1);
                half4v u0 = *(const half4v*)&h[(size_t)s0 * 64 + c0];
                half4v u1 = *(const half4v*)&h[(size_t)s1 * 64 + c0];
                ax += cc0 * (float)u0[0]; ay += cc0 * (float)u0[1];
                az += cc0 * (float)u0[2]; aw += cc0 * (float)u0[3];
                bx += cc1 * (float)u1[0]; by += cc1 * (float)u1[1];
                bz += cc1 * (float)u1[2]; bw += cc1 * (float)u1[3];
            }
            if (e < end) {
                int s0; float cc0;
                unpack_edge(edges[e], s0, cc0);
                half4v u0 = *(const half4v*)&h[(size_t)s0 * 64 + c0];
                ax += cc0 * (float)u0[0]; ay += cc0 * (float)u0[1];
                az += cc0 * (float)u0[2]; aw += cc0 * (float)u0[3];
            }
            ax = fmaxf(ax + bx + bv.x, 0.f);
            ay = fmaxf(ay + by + bv.y, 0.f);
            az = fmaxf(az + bz + bv.z, 0.f);
            aw = fmaxf(aw + bw + bv.w, 0.f);
        }
        oT[(c0 + 0) * 68 + ni] = ax;
        oT[(c0 + 1) * 68 + ni] = ay;
        oT[(c0 + 2) * 68 + ni] = az;
        oT[(c0 + 3) * 68 + ni] = aw;
    }
    __syncthreads();
    float acc[4][4] = {};
    const float* otp = &oT[ng * 4];
    const float* wsp = &Ws[cg * 4];
    #pragma unroll 2
    for (int k = 0; k < 64; ++k) {
        float4 ov = *(const float4*)&otp[k * 68];
        float4 wv = *(const float4*)&wsp[k * 64];
        #pragma unroll
        for (int i = 0; i < 4; ++i) {
            float o = (&ov.x)[i];
            acc[i][0] += o * wv.x;
            acc[i][1] += o * wv.y;
            acc[i][2] += o * wv.z;
            acc[i][3] += o * wv.w;
        }
    }
    #pragma unroll
    for (int i = 0; i < 4; ++i) {
        float4 p;
        p.x = fmaxf(acc[i][0], 0.f);
        p.y = fmaxf(acc[i][1], 0.f);
        p.z = fmaxf(acc[i][2], 0.f);
        p.w = fmaxf(acc[i][3], 0.f);
        float ss = p.x * p.x + p.y * p.y + p.z * p.z + p.w * p.w;
        #pragma unroll
        for (int off = 1; off < 16; off <<= 1) ss += __shfl_xor(ss, off, 64);
        float norm = sqrtf(ss);
        float sc = 1.0f / fmaxf(norm, 1e-12f);
        int node = base + ng * 4 + i;
        if (node < n) {
            p.x *= sc; p.y *= sc; p.z *= sc; p.w *= sc;
            *(float4*)&P[(size_t)node * 64 + cg * 4] = p;
        }
    }
}

// ---------------- launch ----------------

static inline size_t ws_align(size_t x) { return (x + 255) & ~(size_t)255; }

extern "C" void kernel_launch(void* const* d_in, const int* in_sizes, int n_in,
                              void* d_out, int out_size, void* d_ws, size_t ws_size,
                              hipStream_t stream) {
    const float* x  = (const float*)d_in[0];
    const int*   ei = (const int*)d_in[1];
    const float* W1 = (const float*)d_in[2];
    const float* b1 = (const float*)d_in[3];
    const float* W2 = (const float*)d_in[4];
    const float* b2 = (const float*)d_in[5];
    const float* W3 = (const float*)d_in[6];
    const float* b3 = (const float*)d_in[7];
    const float* Wp = (const float*)d_in[8];

    int n = in_sizes[0] / 128;
    int E = in_sizes[1] / 2;
    const int* src = ei;
    const int* dst = ei + E;

    char* ws = (char*)d_ws;
    size_t off = 0;
    auto alloc = [&](size_t bytes) -> void* {
        void* p = ws + off;
        off = ws_align(off + bytes);
        return p;
    };
    _Float16* bufA = (_Float16*)alloc((size_t)n * 128 * 2);
    _Float16* bufB = (_Float16*)alloc((size_t)n * 128 * 2);
    _Float16* Wt1  = (_Float16*)alloc(128 * 128 * 2);
    _Float16* Wt2  = (_Float16*)alloc(128 * 128 * 2);
    _Float16* Wt3  = (_Float16*)alloc(64 * 128 * 2);
    int*   cnt      = (int*)alloc((size_t)n * 4);
    float* dis      = (float*)alloc((size_t)n * 4);
    int*   row_ptr  = (int*)alloc((size_t)(n + 1) * 4);
    unsigned short* rank = (unsigned short*)alloc((size_t)E * 2);
    unsigned int* edges = (unsigned int*)alloc((size_t)E * 4);
    int*   blockSums = (int*)alloc(256);
    (void)off; (void)ws_size;

    int B = (n + 1023) / 1024;
    int wz = 40960 + n;
    cvt_wz<<<(wz + 255) / 256, 256, 0, stream>>>(W1, W2, W3, Wt1, Wt2, Wt3, cnt, n);
    count_rank<<<(E + 255) / 256, 256, 0, stream>>>(dst, E, cnt, rank);
    scanA<<<B, 256, 0, stream>>>(cnt, row_ptr, blockSums, dis, n);
    scanC<<<B, 256, 0, stream>>>(row_ptr, blockSums, n, E, B);
    fill_nr<<<(E + 255) / 256, 256, 0, stream>>>(src, dst, rank, E, row_ptr, dis, edges);

    int gblocks = (n + 63) / 64;
    int fblocks = (n + 15) / 16;
    int pblocks = (n + 63) / 64;
    float* outp = (float*)d_out;

    gemm_mfma<128, true><<<gblocks, 256, 0, stream>>>(x, Wt1, bufA, n);
    agg_gemm<128><<<fblocks, 1024, 0, stream>>>(bufA, row_ptr, edges, dis, b1, Wt2, bufB, n);
    agg_gemm<64><<<fblocks, 1024, 0, stream>>>(bufB, row_ptr, edges, dis, b2, Wt3, bufA, n);
    agg_proj<<<pblocks, 256, 0, stream>>>(bufA, row_ptr, edges, dis, b3, Wp, outp, n);
}

// Round 16
// 211.893 us; speedup vs baseline: 2.3763x; 1.0374x over previous
//
#include <hip/hip_runtime.h>
#include <hip/hip_fp16.h>

typedef _Float16 half8v __attribute__((ext_vector_type(8)));
typedef _Float16 half4v __attribute__((ext_vector_type(4)));
typedef _Float16 half2v __attribute__((ext_vector_type(2)));
typedef float f32x4 __attribute__((ext_vector_type(4)));

// ---------------- fused: transpose-convert W1/W2/W3 to fp16 Wt[N][128] + zero cnt ----------------

__global__ void cvt_wz(const float* __restrict__ W1, const float* __restrict__ W2,
                       const float* __restrict__ W3,
                       _Float16* __restrict__ Wt1, _Float16* __restrict__ Wt2,
                       _Float16* __restrict__ Wt3,
                       int* __restrict__ cnt, int n) {
    int i = blockIdx.x * blockDim.x + threadIdx.x;
    if (i < 16384) {
        int nn = i >> 7, kk = i & 127;
        Wt1[i] = (_Float16)W1[kk * 128 + nn];
    } else if (i < 32768) {
        int j = i - 16384; int nn = j >> 7, kk = j & 127;
        Wt2[j] = (_Float16)W2[kk * 128 + nn];
    } else if (i < 40960) {
        int j = i - 32768; int nn = j >> 7, kk = j & 127;
        Wt3[j] = (_Float16)W3[kk * 64 + nn];
    }
    int z = i - 40960;
    if (z >= 0 && z < n) cnt[z] = 0;
}

// ---------------- degree count; atomic's return value IS the edge's rank in its row ----------------

__global__ void count_rank(const int* __restrict__ dst, int E, int* __restrict__ cnt,
                           unsigned short* __restrict__ rank) {
    int e = blockIdx.x * blockDim.x + threadIdx.x;
    if (e < E) rank[e] = (unsigned short)atomicAdd(&cnt[dst[e]], 1);
}

// scanA: block-local exclusive scan of cnt + dis = rsqrt(deg+1)
__global__ __launch_bounds__(256) void scanA(const int* __restrict__ cnt,
                                             int* __restrict__ row_ptr,
                                             int* __restrict__ blockSums,
                                             float* __restrict__ dis, int n) {
    __shared__ int s[256];
    int t = threadIdx.x;
    int base = blockIdx.x * 1024 + t * 4;
    int v0 = (base + 0 < n) ? cnt[base + 0] : 0;
    int v1 = (base + 1 < n) ? cnt[base + 1] : 0;
    int v2 = (base + 2 < n) ? cnt[base + 2] : 0;
    int v3 = (base + 3 < n) ? cnt[base + 3] : 0;
    if (base + 0 < n) dis[base + 0] = rsqrtf((float)(v0 + 1));
    if (base + 1 < n) dis[base + 1] = rsqrtf((float)(v1 + 1));
    if (base + 2 < n) dis[base + 2] = rsqrtf((float)(v2 + 1));
    if (base + 3 < n) dis[base + 3] = rsqrtf((float)(v3 + 1));
    int tsum = v0 + v1 + v2 + v3;
    s[t] = tsum;
    __syncthreads();
    for (int off = 1; off < 256; off <<= 1) {
        int u = (t >= off) ? s[t - off] : 0;
        __syncthreads();
        s[t] += u;
        __syncthreads();
    }
    int excl = s[t] - tsum;
    if (base + 0 < n) row_ptr[base + 0] = excl;
    if (base + 1 < n) row_ptr[base + 1] = excl + v0;
    if (base + 2 < n) row_ptr[base + 2] = excl + v0 + v1;
    if (base + 3 < n) row_ptr[base + 3] = excl + v0 + v1 + v2;
    if (t == 255) blockSums[blockIdx.x] = s[255];
}

// scanC with inlined block-sum scan (B <= 64 blocks)
__global__ __launch_bounds__(256) void scanC(int* __restrict__ row_ptr,
                                             const int* __restrict__ blockSums,
                                             int n, int E, int B) {
    __shared__ int soff;
    int t = threadIdx.x;
    if (t < 64) {
        int v = (t < B) ? blockSums[t] : 0;
        int orig = v;
        for (int off = 1; off < 64; off <<= 1) {
            int u = __shfl_up(v, off, 64);
            if (t >= off) v += u;
        }
        if (t == (int)blockIdx.x) soff = v - orig;
    }
    __syncthreads();
    int off = soff;
    int base = blockIdx.x * 1024 + t * 4;
    #pragma unroll
    for (int j = 0; j < 4; ++j)
        if (base + j < n) row_ptr[base + j] += off;
    if (blockIdx.x == 0 && t == 0) row_ptr[n] = E;
}

// atomic-free CSR fill: slot = row_ptr[d] + rank[e]
__global__ void fill_nr(const int* __restrict__ src, const int* __restrict__ dst,
                        const unsigned short* __restrict__ rank, int E,
                        const int* __restrict__ row_ptr, const float* __restrict__ dis,
                        unsigned int* __restrict__ edges) {
    int e = blockIdx.x * blockDim.x + threadIdx.x;
    if (e >= E) return;
    int d = dst[e], s = src[e];
    int slot = row_ptr[d] + (int)rank[e];
    float coef = dis[s] * dis[d];
    edges[slot] = (unsigned)s |
                  ((unsigned)__half_as_ushort(__float2half_rn(coef)) << 16);
}

__device__ __forceinline__ void unpack_edge(unsigned int w, int& s, float& c) {
    s = (int)(w & 0xffffu);
    c = __half2float(__ushort_as_half((unsigned short)(w >> 16)));
}

// ---------------- MFMA GEMM layer 1: Y[M,128](fp16) = f32 x @ Wt1[128][128] ----------------

template <int N, bool F32IN>
__global__ __launch_bounds__(256) void gemm_mfma(const void* __restrict__ Xin,
                                                 const _Float16* __restrict__ Wt,
                                                 _Float16* __restrict__ Y, int M) {
    constexpr int NT = N / 16;
    int wave = threadIdx.x >> 6;
    int lane = threadIdx.x & 63;
    int m0 = blockIdx.x * 64 + wave * 16;
    int r = lane & 15;
    int kb = lane >> 4;
    int ar = m0 + r; if (ar >= M) ar = M - 1;
    f32x4 acc[NT] = {};
    #pragma unroll
    for (int kk = 0; kk < 128; kk += 32) {
        half8v a;
        if constexpr (F32IN) {
            const float* arow = (const float*)Xin + (size_t)ar * 128 + kb * 8 + kk;
            float4 f0 = *(const float4*)arow;
            float4 f1 = *(const float4*)(arow + 4);
            a = (half8v){(_Float16)f0.x, (_Float16)f0.y, (_Float16)f0.z, (_Float16)f0.w,
                         (_Float16)f1.x, (_Float16)f1.y, (_Float16)f1.z, (_Float16)f1.w};
        } else {
            a = *(const half8v*)((const _Float16*)Xin + (size_t)ar * 128 + kb * 8 + kk);
        }
        #pragma unroll
        for (int c = 0; c < NT; ++c) {
            half8v b = *(const half8v*)(Wt + (size_t)(c * 16 + r) * 128 + kk + kb * 8);
            acc[c] = __builtin_amdgcn_mfma_f32_16x16x32_f16(a, b, acc[c], 0, 0, 0);
        }
    }
    #pragma unroll
    for (int j = 0; j < 4; ++j) {
        int row = m0 + kb * 4 + j;
        if (row < M) {
            #pragma unroll
            for (int c = 0; c < NT; ++c)
                Y[(size_t)row * N + c * 16 + r] = (_Float16)acc[c][j];
        }
    }
}

// ---------------- FUSED agg(D=128) + GEMM: register edge cache + quad-edge gather ----------------
// 1024 thr = 16 waves, one node per wave. Edge words for the whole row (deg<=64) are
// loaded by ONE coalesced load into the wave's lanes, then distributed via __shfl
// (pure VALU, no memory dependence) -> all row-gather loads are independent.
// Lane layout: grp = lane>>4 picks edge slot, sub = lane&15 picks 16B of the 256B row.

template <int NOUT>
__global__ __launch_bounds__(1024) void agg_gemm(const _Float16* __restrict__ h,
                                                 const int* __restrict__ row_ptr,
                                                 const unsigned int* __restrict__ edges,
                                                 const float* __restrict__ dis,
                                                 const float* __restrict__ bias,
                                                 const _Float16* __restrict__ Wt,
                                                 _Float16* __restrict__ Y, int n) {
    __shared__ _Float16 As[16][136];
    int t = threadIdx.x;
    int wave = t >> 6;
    int lane = t & 63;
    int m0 = blockIdx.x * 16;
    int node = m0 + wave;
    int grp = lane >> 4;   // edge slot 0..3
    int sub = lane & 15;   // dim quad: dims sub*8 .. sub*8+7
    if (node < n) {
        int beg = row_ptr[node], end = row_ptr[node + 1];
        int deg = end - beg;
        float di = dis[node];
        float cs = di * di;
        float acc[8] = {0.f, 0.f, 0.f, 0.f, 0.f, 0.f, 0.f, 0.f};
        if (grp == 0) {
            half8v sv = *(const half8v*)(h + (size_t)node * 128 + sub * 8);
            #pragma unroll
            for (int j = 0; j < 8; ++j) acc[j] = cs * (float)sv[j];
        }
        // register edge cache: one coalesced load covers the whole row (deg<=64)
        unsigned int w_all = (lane < deg) ? edges[beg + lane] : 0u;
        int dmax = min(deg, 64);
        for (int i = 0; i < dmax; i += 8) {
            int i0 = i + grp, i1 = i + 4 + grp;
            unsigned int wi0 = __shfl(w_all, i0, 64);
            unsigned int wi1 = __shfl(w_all, i1, 64);
            int s0, s1; float c0, c1;
            unpack_edge(wi0, s0, c0);
            unpack_edge(wi1, s1, c1);
            if (i0 < dmax) {
                half8v u0 = *(const half8v*)(h + (size_t)s0 * 128 + sub * 8);
                #pragma unroll
                for (int j = 0; j < 8; ++j) acc[j] += c0 * (float)u0[j];
            }
            if (i1 < dmax) {
                half8v u1 = *(const half8v*)(h + (size_t)s1 * 128 + sub * 8);
                #pragma unroll
                for (int j = 0; j < 8; ++j) acc[j] += c1 * (float)u1[j];
            }
        }
        // tail for deg > 64 (vanishingly rare)
        for (int e = beg + 64; e < end; e += 4) {
            int ee = e + grp;
            float c0 = 0.f; int s0 = node;
            if (ee < end) { unsigned int w = edges[ee]; unpack_edge(w, s0, c0); }
            half8v u0 = *(const half8v*)(h + (size_t)s0 * 128 + sub * 8);
            #pragma unroll
            for (int j = 0; j < 8; ++j) acc[j] += c0 * (float)u0[j];
        }
        // combine the 4 edge-groups (lanes xor 16, xor 32 hold same sub)
        #pragma unroll
        for (int j = 0; j < 8; ++j) {
            acc[j] += __shfl_xor(acc[j], 16, 64);
            acc[j] += __shfl_xor(acc[j], 32, 64);
        }
        if (grp == 0) {
            float4 b0 = *(const float4*)&bias[sub * 8];
            float4 b1 = *(const float4*)&bias[sub * 8 + 4];
            half8v o;
            o[0] = (_Float16)fmaxf(acc[0] + b0.x, 0.f);
            o[1] = (_Float16)fmaxf(acc[1] + b0.y, 0.f);
            o[2] = (_Float16)fmaxf(acc[2] + b0.z, 0.f);
            o[3] = (_Float16)fmaxf(acc[3] + b0.w, 0.f);
            o[4] = (_Float16)fmaxf(acc[4] + b1.x, 0.f);
            o[5] = (_Float16)fmaxf(acc[5] + b1.y, 0.f);
            o[6] = (_Float16)fmaxf(acc[6] + b1.z, 0.f);
            o[7] = (_Float16)fmaxf(acc[7] + b1.w, 0.f);
            *(half8v*)&As[wave][sub * 8] = o;
        }
    } else if (lane < 16) {
        half8v z = {};
        *(half8v*)&As[wave][sub * 8] = z;
    }
    __syncthreads();
    constexpr int CT = NOUT / 16;  // 8 or 4 col tiles
    if (wave < CT) {
        int r = lane & 15;
        int kb = lane >> 4;
        f32x4 acc = {};
        #pragma unroll
        for (int kk = 0; kk < 128; kk += 32) {
            half8v a = *(const half8v*)&As[r][kb * 8 + kk];
            half8v b = *(const half8v*)(Wt + (size_t)(wave * 16 + r) * 128 + kk + kb * 8);
            acc = __builtin_amdgcn_mfma_f32_16x16x32_f16(a, b, acc, 0, 0, 0);
        }
        #pragma unroll
        for (int j = 0; j < 4; ++j) {
            int row = m0 + kb * 4 + j;
            if (row < n)
                Y[(size_t)row * NOUT + wave * 16 + r] = (_Float16)acc[j];
        }
    }
}

// ---------------- FUSED agg(D=64) + projection + relu + row-normalize ----------------
// block = 64 nodes, 16 threads/node. Register edge cache per 16-edge chunk via
// width-16 shfl; row loads independent. Writes transposed oT then proj as before.

__global__ __launch_bounds__(256) void agg_proj(const _Float16* __restrict__ h,
                                                const int* __restrict__ row_ptr,
                                                const unsigned int* __restrict__ edges,
                                                const float* __restrict__ dis,
                                                const float* __restrict__ b3,
                                                const float* __restrict__ Wp,
                                                float* __restrict__ P, int n) {
    __shared__ float oT[64 * 68];
    __shared__ float Ws[64 * 64];
    int t = threadIdx.x;
    int base = blockIdx.x * 64;
    for (int j = t * 4; j < 4096; j += 1024)
        *(float4*)&Ws[j] = *(const float4*)&Wp[j];
    int cg = t & 15;   // col group: dims 4*cg..+3 (also edge-cache slot)
    int ng = t >> 4;   // node-in-pass 0..15
    int c0 = cg * 4;
    float4 bv = *(const float4*)&b3[c0];
    #pragma unroll
    for (int pass = 0; pass < 4; ++pass) {
        int ni = pass * 16 + ng;
        int node = base + ni;
        float ax = 0.f, ay = 0.f, az = 0.f, aw = 0.f;
        if (node < n) {
            int beg = row_ptr[node], end = row_ptr[node + 1];
            float di = dis[node];
            float cs = di * di;
            half4v sv = *(const half4v*)&h[(size_t)node * 64 + c0];
            ax = cs * (float)sv[0]; ay = cs * (float)sv[1];
            az = cs * (float)sv[2]; aw = cs * (float)sv[3];
            float bx = 0.f, by = 0.f, bz = 0.f, bw = 0.f;
            for (int eb = beg; eb < end; eb += 16) {
                int cnt16 = min(16, end - eb);
                unsigned int w16 = (cg < cnt16) ? edges[eb + cg] : 0u;
                for (int i = 0; i < cnt16; i += 2) {
                    int s0, s1; float cc0, cc1;
                    unpack_edge(__shfl(w16, i, 16), s0, cc0);
                    unpack_edge(__shfl(w16, i + 1, 16), s1, cc1);
                    half4v u0 = *(const half4v*)&h[(size_t)s0 * 64 + c0];
                    ax += cc0 * (float)u0[0]; ay += cc0 * (float)u0[1];
                    az += cc0 * (float)u0[2]; aw += cc0 * (float)u0[3];
                    if (i + 1 < cnt16) {
                        half4v u1 = *(const half4v*)&h[(size_t)s1 * 64 + c0];
                        bx += cc1 * (float)u1[0]; by += cc1 * (float)u1[1];
                        bz += cc1 * (float)u1[2]; bw += cc1 * (float)u1[3];
                    }
                }
            }
            ax = fmaxf(ax + bx + bv.x, 0.f);
            ay = fmaxf(ay + by + bv.y, 0.f);
            az = fmaxf(az + bz + bv.z, 0.f);
            aw = fmaxf(aw + bw + bv.w, 0.f);
        }
        oT[(c0 + 0) * 68 + ni] = ax;
        oT[(c0 + 1) * 68 + ni] = ay;
        oT[(c0 + 2) * 68 + ni] = az;
        oT[(c0 + 3) * 68 + ni] = aw;
    }
    __syncthreads();
    float acc[4][4] = {};
    const float* otp = &oT[ng * 4];
    const float* wsp = &Ws[cg * 4];
    #pragma unroll 2
    for (int k = 0; k < 64; ++k) {
        float4 ov = *(const float4*)&otp[k * 68];
        float4 wv = *(const float4*)&wsp[k * 64];
        #pragma unroll
        for (int i = 0; i < 4; ++i) {
            float o = (&ov.x)[i];
            acc[i][0] += o * wv.x;
            acc[i][1] += o * wv.y;
            acc[i][2] += o * wv.z;
            acc[i][3] += o * wv.w;
        }
    }
    #pragma unroll
    for (int i = 0; i < 4; ++i) {
        float4 p;
        p.x = fmaxf(acc[i][0], 0.f);
        p.y = fmaxf(acc[i][1], 0.f);
        p.z = fmaxf(acc[i][2], 0.f);
        p.w = fmaxf(acc[i][3], 0.f);
        float ss = p.x * p.x + p.y * p.y + p.z * p.z + p.w * p.w;
        #pragma unroll
        for (int off = 1; off < 16; off <<= 1) ss += __shfl_xor(ss, off, 64);
        float norm = sqrtf(ss);
        float sc = 1.0f / fmaxf(norm, 1e-12f);
        int node = base + ng * 4 + i;
        if (node < n) {
            p.x *= sc; p.y *= sc; p.z *= sc; p.w *= sc;
            *(float4*)&P[(size_t)node * 64 + cg * 4] = p;
        }
    }
}

// ---------------- launch ----------------

static inline size_t ws_align(size_t x) { return (x + 255) & ~(size_t)255; }

extern "C" void kernel_launch(void* const* d_in, const int* in_sizes, int n_in,
                              void* d_out, int out_size, void* d_ws, size_t ws_size,
                              hipStream_t stream) {
    const float* x  = (const float*)d_in[0];
    const int*   ei = (const int*)d_in[1];
    const float* W1 = (const float*)d_in[2];
    const float* b1 = (const float*)d_in[3];
    const float* W2 = (const float*)d_in[4];
    const float* b2 = (const float*)d_in[5];
    const float* W3 = (const float*)d_in[6];
    const float* b3 = (const float*)d_in[7];
    const float* Wp = (const float*)d_in[8];

    int n = in_sizes[0] / 128;
    int E = in_sizes[1] / 2;
    const int* src = ei;
    const int* dst = ei + E;

    char* ws = (char*)d_ws;
    size_t off = 0;
    auto alloc = [&](size_t bytes) -> void* {
        void* p = ws + off;
        off = ws_align(off + bytes);
        return p;
    };
    _Float16* bufA = (_Float16*)alloc((size_t)n * 128 * 2);
    _Float16* bufB = (_Float16*)alloc((size_t)n * 128 * 2);
    _Float16* Wt1  = (_Float16*)alloc(128 * 128 * 2);
    _Float16* Wt2  = (_Float16*)alloc(128 * 128 * 2);
    _Float16* Wt3  = (_Float16*)alloc(64 * 128 * 2);
    int*   cnt      = (int*)alloc((size_t)n * 4);
    float* dis      = (float*)alloc((size_t)n * 4);
    int*   row_ptr  = (int*)alloc((size_t)(n + 1) * 4);
    unsigned short* rank = (unsigned short*)alloc((size_t)E * 2);
    unsigned int* edges = (unsigned int*)alloc((size_t)E * 4);
    int*   blockSums = (int*)alloc(256);
    (void)off; (void)ws_size;

    int B = (n + 1023) / 1024;
    int wz = 40960 + n;
    cvt_wz<<<(wz + 255) / 256, 256, 0, stream>>>(W1, W2, W3, Wt1, Wt2, Wt3, cnt, n);
    count_rank<<<(E + 255) / 256, 256, 0, stream>>>(dst, E, cnt, rank);
    scanA<<<B, 256, 0, stream>>>(cnt, row_ptr, blockSums, dis, n);
    scanC<<<B, 256, 0, stream>>>(row_ptr, blockSums, n, E, B);
    fill_nr<<<(E + 255) / 256, 256, 0, stream>>>(src, dst, rank, E, row_ptr, dis, edges);

    int gblocks = (n + 63) / 64;
    int fblocks = (n + 15) / 16;
    int pblocks = (n + 63) / 64;
    float* outp = (float*)d_out;

    gemm_mfma<128, true><<<gblocks, 256, 0, stream>>>(x, Wt1, bufA, n);
    agg_gemm<128><<<fblocks, 1024, 0, stream>>>(bufA, row_ptr, edges, dis, b1, Wt2, bufB, n);
    agg_gemm<64><<<fblocks, 1024, 0, stream>>>(bufB, row_ptr, edges, dis, b2, Wt3, bufA, n);
    agg_proj<<<pblocks, 256, 0, stream>>>(bufA, row_ptr, edges, dis, b3, Wp, outp, n);
}